// Round 1
// baseline (5356.518 us; speedup 1.0000x reference)
//
#include <hip/hip_runtime.h>

#define N_NODES 51200
#define N_EDGES 614400
#define ORIG 92
#define AFL 64
#define NFL 64
#define BINS 100
#define NCONV 3
#define BN_EPS 1e-5f

// ---------- helpers: bf16 pack/unpack (bf16 = top 16 bits of fp32) ----------
__device__ __forceinline__ float bflo(unsigned int u) { return __uint_as_float(u << 16); }
__device__ __forceinline__ float bfhi(unsigned int u) { return __uint_as_float(u & 0xffff0000u); }
__device__ __forceinline__ unsigned int f2bf(float f) {
    unsigned int u = __float_as_uint(f);
    return (u + 0x7fffu + ((u >> 16) & 1u)) >> 16;   // RNE
}
__device__ __forceinline__ unsigned int pack2(float a, float b) {
    return f2bf(a) | (f2bf(b) << 16);
}

// ---------------------------- embedding ----------------------------
// h0[n][f] = emb_b[f] + sum_k x[n][k]*att[k]*emb_W[k][f]
__global__ __launch_bounds__(256) void embed_kernel(
    const float* __restrict__ x, const float* __restrict__ att,
    const float* __restrict__ W, const float* __restrict__ b,
    float* __restrict__ h0)
{
    const int wave = threadIdx.x >> 6, lane = threadIdx.x & 63;
    const int gw = blockIdx.x * 4 + wave;
    const float bv = b[lane];
    for (int n = gw; n < N_NODES; n += gridDim.x * 4) {
        const float* xr = x + (size_t)n * ORIG;
        float acc = bv;
        for (int k = 0; k < ORIG; ++k)
            acc = fmaf(xr[k] * att[k], W[k * AFL + lane], acc);
        h0[(size_t)n * AFL + lane] = acc;
    }
}

// ---------------------------- fused edge kernel ----------------------------
// per edge: v2 = leakyrelu(a*w1+b1); v3 = v2@W2 + b2 + alpha*v2; p = softmax(v3);
// e = p@lut; z = [h[dst], h[src], e] @ fcW + fcb; store z (bf16x2), accumulate bn1 stats.
#define EK_GRID  256
#define EK_BLOCK 512
#define EK_WAVES 8
#define E_PER    4
#define EK_TILES (EK_GRID * EK_WAVES)                 // 2048
#define EK_ITERS (N_EDGES / (EK_TILES * E_PER))       // 75

__global__ __launch_bounds__(EK_BLOCK, 1) void edge_kernel(
    const float* __restrict__ ea, const int* __restrict__ ei,
    const float* __restrict__ h,
    const float* __restrict__ w1, const float* __restrict__ b1,
    const float* __restrict__ w2, const float* __restrict__ b2,
    const float* __restrict__ alpha_p, const float* __restrict__ lut,
    const float* __restrict__ fcW, const float* __restrict__ fcb,
    unsigned int* __restrict__ zout, float* __restrict__ stats)
{
    __shared__ unsigned int sW2u[BINS * 50];          // bf16 pairs of W2[k][2j..2j+1]  20000B
    __shared__ float        sLut[BINS * NFL];         // 25600B
    __shared__ unsigned int sFcU[192 * 64];           // bf16 pairs of fcW[k][2j..2j+1] 49152B
    __shared__ float        sv2[EK_WAVES][E_PER][BINS];   // v2 then p   12800B
    __shared__ float        scat[EK_WAVES][E_PER][192];   // cat vector  24576B

    const int tid = threadIdx.x;
    for (int i = tid; i < BINS * 50; i += EK_BLOCK) sW2u[i] = pack2(w2[2 * i], w2[2 * i + 1]);
    for (int i = tid; i < BINS * NFL; i += EK_BLOCK) sLut[i] = lut[i];
    for (int i = tid; i < 192 * 64; i += EK_BLOCK) sFcU[i] = pack2(fcW[2 * i], fcW[2 * i + 1]);
    __syncthreads();

    const int wave = tid >> 6, lane = tid & 63;
    const int gw = blockIdx.x * EK_WAVES + wave;
    const float alpha = alpha_p[0];

    const float w1a = w1[lane], b1a = b1[lane];
    const bool has2 = (lane + 64) < BINS;             // lane < 36
    float w1b = 0.f, b1b = 0.f;
    if (has2) { w1b = w1[lane + 64]; b1b = b1[lane + 64]; }
    const int j2 = 2 * lane;
    const bool act = lane < 50;                       // covers v3 cols 0..99
    float b2a = 0.f, b2b = 0.f;
    if (act) { b2a = b2[j2]; b2b = b2[j2 + 1]; }
    const float fb0 = fcb[j2], fb1 = fcb[j2 + 1];

    float ss0 = 0.f, ss1 = 0.f, sq0 = 0.f, sq1 = 0.f;

    for (int it = 0; it < EK_ITERS; ++it) {
        const int ebase = (it * EK_TILES + gw) * E_PER;
        float av[E_PER];
        int sn[E_PER], dn[E_PER];
#pragma unroll
        for (int e = 0; e < E_PER; ++e) {
            av[e] = ea[ebase + e];
            sn[e] = ei[ebase + e];                    // src = x_j
            dn[e] = ei[N_EDGES + ebase + e];          // dst = x_i / aggregation target
        }
        // ---- v2 ----
#pragma unroll
        for (int e = 0; e < E_PER; ++e) {
            float v = fmaf(av[e], w1a, b1a); v = v > 0.f ? v : 0.01f * v;
            sv2[wave][e][lane] = v;
            if (has2) { float u = fmaf(av[e], w1b, b1b); u = u > 0.f ? u : 0.01f * u; sv2[wave][e][lane + 64] = u; }
        }
        __syncthreads();
        // ---- v3 = v2@W2 + b2 + alpha*v2 (lane < 50 owns cols 2j,2j+1) ----
        float acc0[E_PER], acc1[E_PER];
#pragma unroll
        for (int e = 0; e < E_PER; ++e) {
            if (act) {
                acc0[e] = fmaf(alpha, sv2[wave][e][j2], b2a);
                acc1[e] = fmaf(alpha, sv2[wave][e][j2 + 1], b2b);
            } else { acc0[e] = -INFINITY; acc1[e] = -INFINITY; }
        }
        for (int k4 = 0; k4 < BINS; k4 += 4) {
            float4 vb[E_PER];
#pragma unroll
            for (int e = 0; e < E_PER; ++e) vb[e] = *(const float4*)&sv2[wave][e][k4];
            if (act) {
#pragma unroll
                for (int kk = 0; kk < 4; ++kk) {
                    unsigned int wp = sW2u[(k4 + kk) * 50 + lane];
                    float wl = bflo(wp), wh = bfhi(wp);
#pragma unroll
                    for (int e = 0; e < E_PER; ++e) {
                        float v = ((const float*)&vb[e])[kk];
                        acc0[e] = fmaf(v, wl, acc0[e]);
                        acc1[e] = fmaf(v, wh, acc1[e]);
                    }
                }
            }
        }
        __syncthreads();
        // ---- softmax over 100 bins (wave reduction) ----
        float p0[E_PER], p1[E_PER];
#pragma unroll
        for (int e = 0; e < E_PER; ++e) {
            float m = fmaxf(acc0[e], acc1[e]);
#pragma unroll
            for (int o = 32; o >= 1; o >>= 1) m = fmaxf(m, __shfl_xor(m, o, 64));
            float e0 = __expf(acc0[e] - m), e1 = __expf(acc1[e] - m);
            float s = e0 + e1;
#pragma unroll
            for (int o = 32; o >= 1; o >>= 1) s += __shfl_xor(s, o, 64);
            float inv = 1.0f / s;
            p0[e] = e0 * inv; p1[e] = e1 * inv;
        }
        // write p (reuse sv2) + gather h rows
#pragma unroll
        for (int e = 0; e < E_PER; ++e) {
            if (act) { float2 pp; pp.x = p0[e]; pp.y = p1[e]; *(float2*)&sv2[wave][e][j2] = pp; }
            scat[wave][e][lane]       = h[(size_t)dn[e] * AFL + lane];
            scat[wave][e][AFL + lane] = h[(size_t)sn[e] * AFL + lane];
        }
        __syncthreads();
        // ---- e = p @ lut (lane owns feature f=lane) ----
        float ef[E_PER] = {0.f, 0.f, 0.f, 0.f};
        for (int k4 = 0; k4 < BINS; k4 += 4) {
            float4 pb[E_PER];
#pragma unroll
            for (int e = 0; e < E_PER; ++e) pb[e] = *(const float4*)&sv2[wave][e][k4];
#pragma unroll
            for (int kk = 0; kk < 4; ++kk) {
                float lv = sLut[(k4 + kk) * NFL + lane];
#pragma unroll
                for (int e = 0; e < E_PER; ++e)
                    ef[e] = fmaf(((const float*)&pb[e])[kk], lv, ef[e]);
            }
        }
#pragma unroll
        for (int e = 0; e < E_PER; ++e) scat[wave][e][128 + lane] = ef[e];
        __syncthreads();
        // ---- z = cat @ fcW + fcb (lane owns cols 2j,2j+1) ----
        float z0[E_PER], z1[E_PER];
#pragma unroll
        for (int e = 0; e < E_PER; ++e) { z0[e] = fb0; z1[e] = fb1; }
        for (int k4 = 0; k4 < 192; k4 += 4) {
            float4 cb[E_PER];
#pragma unroll
            for (int e = 0; e < E_PER; ++e) cb[e] = *(const float4*)&scat[wave][e][k4];
#pragma unroll
            for (int kk = 0; kk < 4; ++kk) {
                unsigned int wp = sFcU[(k4 + kk) * 64 + lane];
                float wl = bflo(wp), wh = bfhi(wp);
#pragma unroll
                for (int e = 0; e < E_PER; ++e) {
                    float c = ((const float*)&cb[e])[kk];
                    z0[e] = fmaf(c, wl, z0[e]);
                    z1[e] = fmaf(c, wh, z1[e]);
                }
            }
        }
#pragma unroll
        for (int e = 0; e < E_PER; ++e) {
            ss0 += z0[e]; ss1 += z1[e];
            sq0 = fmaf(z0[e], z0[e], sq0); sq1 = fmaf(z1[e], z1[e], sq1);
            zout[(size_t)(ebase + e) * 64 + lane] = pack2(z0[e], z1[e]);
        }
    }
    atomicAdd(&stats[j2], ss0);
    atomicAdd(&stats[j2 + 1], ss1);
    atomicAdd(&stats[128 + j2], sq0);
    atomicAdd(&stats[128 + j2 + 1], sq1);
}

// ------------- bn finalize: stats[sum C][sq C] -> bnp[scale C][shift C] -------------
__global__ void bn_fin_kernel(const float* __restrict__ stats,
                              const float* __restrict__ g, const float* __restrict__ b,
                              float* __restrict__ bnp, int C, float invN)
{
    int c = threadIdx.x;
    if (c >= C) return;
    float mu = stats[c] * invN;
    float var = stats[C + c] * invN - mu * mu;
    float sc = g[c] * rsqrtf(var + BN_EPS);
    bnp[c] = sc;
    bnp[C + c] = b[c] - mu * sc;
}

// ------------- message + scatter-add: msg = relu(bn(zf))*relu(bn(zc)) -------------
__global__ __launch_bounds__(256) void scatter_kernel(
    const unsigned int* __restrict__ zU, const int* __restrict__ ei,
    const float* __restrict__ bnp, float* __restrict__ aggr)
{
    int t = blockIdx.x * 256 + threadIdx.x;           // E*64 threads
    int e = t >> 6, f = t & 63;
    unsigned int u1 = zU[(size_t)e * 64 + (f >> 1)];
    unsigned int u2 = zU[(size_t)e * 64 + 32 + (f >> 1)];
    float zf = (f & 1) ? bfhi(u1) : bflo(u1);
    float zc = (f & 1) ? bfhi(u2) : bflo(u2);
    zf = fmaf(zf, bnp[f], bnp[128 + f]);
    zc = fmaf(zc, bnp[64 + f], bnp[192 + f]);
    float msg = fmaxf(zf, 0.f) * fmaxf(zc, 0.f);
    int dst = ei[N_EDGES + e];
    atomicAdd(&aggr[(size_t)dst * 64 + f], msg);
}

// ------------- column stats over [rows,64] -------------
__global__ __launch_bounds__(256) void colstats64_kernel(
    const float* __restrict__ x, int rows, float* __restrict__ stats)
{
    int f = threadIdx.x & 63, sub = threadIdx.x >> 6;
    float s = 0.f, q = 0.f;
    for (int r = blockIdx.x * 4 + sub; r < rows; r += gridDim.x * 4) {
        float v = x[(size_t)r * 64 + f];
        s += v; q = fmaf(v, v, q);
    }
    __shared__ float ls[4][64], lq[4][64];
    ls[sub][f] = s; lq[sub][f] = q;
    __syncthreads();
    if (sub == 0) {
        s = ls[0][f] + ls[1][f] + ls[2][f] + ls[3][f];
        q = lq[0][f] + lq[1][f] + lq[2][f] + lq[3][f];
        atomicAdd(&stats[f], s);
        atomicAdd(&stats[64 + f], q);
    }
}

// ------------- h_next = relu(h + bn2(aggr)) -------------
__global__ __launch_bounds__(256) void update_kernel(
    const float* __restrict__ h, const float* __restrict__ aggr,
    const float* __restrict__ bnp, float* __restrict__ hout)
{
    int t = blockIdx.x * 256 + threadIdx.x;           // N*64
    int f = t & 63;
    float v = fmaf(aggr[t], bnp[f], bnp[64 + f]);
    hout[t] = fmaxf(h[t] + v, 0.f);
}

// ------------- pooling: out[b][f] = sum_{layer,atom} softmax(row @ ppW + ppb)[f] -------------
__global__ __launch_bounds__(512, 1) void pool_kernel(
    const float* __restrict__ hbuf, const float* __restrict__ ppW,
    const float* __restrict__ ppb, float* __restrict__ out)
{
    const int b = blockIdx.x;                         // 128 batches
    const int wave = threadIdx.x >> 6, lane = threadIdx.x & 63;
    float wcol[64];
#pragma unroll
    for (int k = 0; k < 64; ++k) wcol[k] = ppW[k * 64 + lane];
    const float bias = ppb[lane];
    float acc = 0.f;
    for (int r = wave; r < 4 * 400; r += 8) {
        int layer = r / 400, atom = r % 400;
        const float* row = hbuf + ((size_t)layer * N_NODES + (size_t)b * 400 + atom) * 64;
        float v = row[lane];
        float logit = bias;
#pragma unroll
        for (int k = 0; k < 64; ++k) logit = fmaf(__shfl(v, k, 64), wcol[k], logit);
        float m = logit;
#pragma unroll
        for (int o = 32; o >= 1; o >>= 1) m = fmaxf(m, __shfl_xor(m, o, 64));
        float ex = __expf(logit - m);
        float s = ex;
#pragma unroll
        for (int o = 32; o >= 1; o >>= 1) s += __shfl_xor(s, o, 64);
        acc += ex * (1.0f / s);
    }
    __shared__ float sacc[8][64];
    sacc[wave][lane] = acc;
    __syncthreads();
    if (wave == 0) {
        float t = 0.f;
#pragma unroll
        for (int w = 0; w < 8; ++w) t += sacc[w][lane];
        out[(size_t)b * 64 + lane] = t;
    }
}

// ---------------------------------------------------------------------------
extern "C" void kernel_launch(void* const* d_in, const int* in_sizes, int n_in,
                              void* d_out, int out_size, void* d_ws, size_t ws_size,
                              hipStream_t stream)
{
    const float* x        = (const float*)d_in[0];
    const int*   ei       = (const int*)d_in[1];
    const float* ea       = (const float*)d_in[2];
    /* d_in[3] = batchsize (128) hardcoded */
    const float* att      = (const float*)d_in[4];
    const float* embW     = (const float*)d_in[5];
    const float* embB     = (const float*)d_in[6];
    const float* ad_w1    = (const float*)d_in[7];
    const float* ad_b1    = (const float*)d_in[8];
    const float* ad_w2    = (const float*)d_in[9];
    const float* ad_b2    = (const float*)d_in[10];
    const float* ad_alpha = (const float*)d_in[11];
    const float* ad_lut   = (const float*)d_in[12];
    const float* fc_W     = (const float*)d_in[13];
    const float* fc_b     = (const float*)d_in[14];
    const float* bn1_g    = (const float*)d_in[15];
    const float* bn1_b    = (const float*)d_in[16];
    const float* bn2_g    = (const float*)d_in[17];
    const float* bn2_b    = (const float*)d_in[18];
    const float* ppW      = (const float*)d_in[19];
    const float* ppb      = (const float*)d_in[20];
    float* out = (float*)d_out;

    char* ws = (char*)d_ws;
    float*        hbuf   = (float*)ws;                                   // 4*N*64 f32 = 52,428,800 B
    unsigned int* zU     = (unsigned int*)(ws + 52428800);               // E*64 u32  = 157,286,400 B
    float*        aggr   = (float*)(ws + 52428800 + 157286400);          // N*64 f32  = 13,107,200 B
    float*        stats1 = (float*)(ws + 222822400);                     // 256 f32
    float*        bnp1   = stats1 + 256;                                 // 256 f32
    float*        stats2 = bnp1 + 256;                                   // 128 f32
    float*        bnp2   = stats2 + 128;                                 // 128 f32

    embed_kernel<<<512, 256, 0, stream>>>(x, att, embW, embB, hbuf);

    for (int l = 0; l < NCONV; ++l) {
        float* h  = hbuf + (size_t)l * N_NODES * AFL;
        float* hn = h + (size_t)N_NODES * AFL;
        hipMemsetAsync(aggr, 0, (size_t)N_NODES * 64 * 4, stream);
        hipMemsetAsync(stats1, 0, 768 * 4, stream);
        edge_kernel<<<EK_GRID, EK_BLOCK, 0, stream>>>(
            ea, ei, h,
            ad_w1 + l * BINS, ad_b1 + l * BINS,
            ad_w2 + l * BINS * BINS, ad_b2 + l * BINS,
            ad_alpha + l, ad_lut + l * BINS * NFL,
            fc_W + l * 192 * 128, fc_b + l * 128,
            zU, stats1);
        bn_fin_kernel<<<1, 128, 0, stream>>>(stats1, bn1_g + l * 128, bn1_b + l * 128,
                                             bnp1, 128, 1.0f / N_EDGES);
        scatter_kernel<<<N_EDGES * 64 / 256, 256, 0, stream>>>(zU, ei, bnp1, aggr);
        colstats64_kernel<<<256, 256, 0, stream>>>(aggr, N_NODES, stats2);
        bn_fin_kernel<<<1, 128, 0, stream>>>(stats2, bn2_g + l * 64, bn2_b + l * 64,
                                             bnp2, 64, 1.0f / N_NODES);
        update_kernel<<<N_NODES * 64 / 256, 256, 0, stream>>>(h, aggr, bnp2, hn);
    }

    pool_kernel<<<128, 512, 0, stream>>>(hbuf, ppW, ppb, out);
}

// Round 2
// 2177.600 us; speedup vs baseline: 2.4598x; 2.4598x over previous
//
#include <hip/hip_runtime.h>

#define N_NODES 51200
#define N_EDGES 614400
#define ORIG 92
#define AFL 64
#define NFL 64
#define BINS 100
#define NCONV 3
#define BN_EPS 1e-5f
#define NTILES (N_EDGES / 16)   // 38400 edge tiles of 16

typedef __attribute__((ext_vector_type(8))) short bf8;   // 8 bf16 (4 VGPRs)
typedef __attribute__((ext_vector_type(4))) float f32x4;

// ---------- bf16 helpers (bf16 = top 16 bits of fp32, RNE) ----------
__device__ __forceinline__ float bflo(unsigned int u) { return __uint_as_float(u << 16); }
__device__ __forceinline__ float bfhi(unsigned int u) { return __uint_as_float(u & 0xffff0000u); }
__device__ __forceinline__ unsigned int f2bf(float f) {
    unsigned int u = __float_as_uint(f);
    return (u + 0x7fffu + ((u >> 16) & 1u)) >> 16;
}
__device__ __forceinline__ short bfs(float f) { return (short)f2bf(f); }
__device__ __forceinline__ unsigned int pack2(float a, float b) {
    return f2bf(a) | (f2bf(b) << 16);
}

// ---------------------------- embedding ----------------------------
__global__ __launch_bounds__(256) void embed_kernel(
    const float* __restrict__ x, const float* __restrict__ att,
    const float* __restrict__ W, const float* __restrict__ b,
    float* __restrict__ h0)
{
    const int wave = threadIdx.x >> 6, lane = threadIdx.x & 63;
    const int gw = blockIdx.x * 4 + wave;
    const float bv = b[lane];
    for (int n = gw; n < N_NODES; n += gridDim.x * 4) {
        const float* xr = x + (size_t)n * ORIG;
        float acc = bv;
        for (int k = 0; k < ORIG; ++k)
            acc = fmaf(xr[k] * att[k], W[k * AFL + lane], acc);
        h0[(size_t)n * AFL + lane] = acc;
    }
}

// ---------------------------- MFMA edge kernel ----------------------------
// wave = one 16-edge tile per iteration. B-weights staged [N][Kpad] bf16 in LDS
// (Kpad = 8 mod 64 elems -> conflict-free b128). A-frag: A[m=lane&15][k=quad*8+j].
// C/D: col=lane&15, row=quad*4+reg.
#define KP2 136   // W2t row stride (K=128 padded)
#define KPL 136   // lutT
#define KPF 200   // fcT  (K=192 padded)
#define SBS 200   // per-wave sBuf row stride (16 rows)

__global__ __launch_bounds__(512, 1) void edge_kernel(
    const float* __restrict__ ea, const int* __restrict__ ei,
    const float* __restrict__ h,
    const float* __restrict__ w1, const float* __restrict__ b1,
    const float* __restrict__ w2, const float* __restrict__ b2,
    const float* __restrict__ alpha_p, const float* __restrict__ lut,
    const float* __restrict__ fcW, const float* __restrict__ fcb,
    short* __restrict__ zo, float* __restrict__ stats)
{
    __shared__ short sW2[112 * KP2];      // 30464 B
    __shared__ short sLut[64 * KPL];      // 17408 B
    __shared__ short sFc[128 * KPF];      // 51200 B
    __shared__ short sBuf[8][16 * SBS];   // 51200 B   total 150272 B

    const int tid = threadIdx.x;
    // ---- stage weights transposed to [N][K] bf16 ----
    for (int i = tid; i < 112 * 128; i += 512) {
        int n = i >> 7, k = i & 127;
        float v = (n < BINS && k < BINS) ? w2[k * BINS + n] : 0.f;
        sW2[n * KP2 + k] = bfs(v);
    }
    for (int i = tid; i < 64 * 128; i += 512) {
        int f = i >> 7, k = i & 127;
        float v = (k < BINS) ? lut[k * NFL + f] : 0.f;
        sLut[f * KPL + k] = bfs(v);
    }
    for (int i = tid; i < 128 * 192; i += 512) {
        int n = i / 192, k = i - n * 192;
        sFc[n * KPF + k] = bfs(fcW[k * 128 + n]);
    }
    __syncthreads();

    const int wave = tid >> 6, lane = tid & 63;
    const int ln = lane & 15, q = lane >> 4;
    short* sB = &sBuf[wave][0];
    const float alpha = alpha_p[0];

    // per-lane constants
    float w1r[32], b1r[32];                 // A-layout v2: k = 32s + 8q + j
#pragma unroll
    for (int s = 0; s < 4; ++s)
#pragma unroll
        for (int j = 0; j < 8; ++j) {
            int k = 32 * s + 8 * q + j;
            bool v = k < BINS;
            w1r[s * 8 + j] = v ? w1[k] : 0.f;
            b1r[s * 8 + j] = v ? b1[k] : 0.f;
        }
    float w1c[7], b1c[7], b2c[7];           // C-layout col = ln + 16t
#pragma unroll
    for (int t = 0; t < 7; ++t) {
        int c = ln + 16 * t;
        bool v = c < BINS;
        w1c[t] = v ? w1[c] : 0.f;
        b1c[t] = v ? b1[c] : 0.f;
        b2c[t] = v ? b2[c] : 0.f;
    }
    float fbias[8];
#pragma unroll
    for (int t = 0; t < 8; ++t) fbias[t] = fcb[ln + 16 * t];

    float ss[8], sq[8];
#pragma unroll
    for (int t = 0; t < 8; ++t) { ss[t] = 0.f; sq[t] = 0.f; }

    for (int tile = blockIdx.x * 8 + wave; tile < NTILES; tile += 2048) {
        __syncthreads();                               // protect sBuf WAR vs prev z-readout
        const int ebase = tile * 16;
        const float av = ea[ebase + ln];
        const int sn = ei[ebase + ln];
        const int dn = ei[N_EDGES + ebase + ln];

        // ---- v3 = v2@W2 + b2 + alpha*v2 ----
        f32x4 acc[7];
#pragma unroll
        for (int t = 0; t < 7; ++t) {
#pragma unroll
            for (int r = 0; r < 4; ++r) {
                float ar = __shfl(av, q * 4 + r, 64);
                float v2c = fmaf(ar, w1c[t], b1c[t]);
                v2c = v2c > 0.f ? v2c : 0.01f * v2c;
                acc[t][r] = fmaf(alpha, v2c, b2c[t]);
            }
        }
#pragma unroll
        for (int s = 0; s < 4; ++s) {
            bf8 a2;
#pragma unroll
            for (int j = 0; j < 8; ++j) {
                float v = fmaf(av, w1r[s * 8 + j], b1r[s * 8 + j]);
                v = v > 0.f ? v : 0.01f * v;
                a2[j] = bfs(v);
            }
#pragma unroll
            for (int t = 0; t < 7; ++t) {
                bf8 bw = *(const bf8*)&sW2[(16 * t + ln) * KP2 + 32 * s + 8 * q];
                acc[t] = __builtin_amdgcn_mfma_f32_16x16x32_bf16(a2, bw, acc[t], 0, 0, 0);
            }
        }
        // ---- softmax over 100 bins (C layout; row-group = 16 lanes) ----
#pragma unroll
        for (int r = 0; r < 4; ++r) {
            float m = -3.4e38f;
#pragma unroll
            for (int t = 0; t < 7; ++t)
                if (t < 6 || ln < 4) m = fmaxf(m, acc[t][r]);
#pragma unroll
            for (int o = 8; o >= 1; o >>= 1) m = fmaxf(m, __shfl_xor(m, o, 16));
            float ev[7], s = 0.f;
#pragma unroll
            for (int t = 0; t < 7; ++t) {
                ev[t] = (t < 6 || ln < 4) ? __expf(acc[t][r] - m) : 0.f;
                s += ev[t];
            }
#pragma unroll
            for (int o = 8; o >= 1; o >>= 1) s += __shfl_xor(s, o, 16);
            float inv = 1.0f / s;
#pragma unroll
            for (int t = 0; t < 7; ++t)
                if (t < 6 || ln < 4) sB[(q * 4 + r) * SBS + ln + 16 * t] = bfs(ev[t] * inv);
        }
        // zero-pad p cols [100,128)
        for (int i = lane; i < 16 * 28; i += 64) {
            int row = i / 28, c = 100 + (i - row * 28);
            sB[row * SBS + c] = 0;
        }
        __syncthreads();
        // ---- e = p @ lut ----
        f32x4 eacc[4];
#pragma unroll
        for (int t = 0; t < 4; ++t) eacc[t] = (f32x4){0.f, 0.f, 0.f, 0.f};
#pragma unroll
        for (int s = 0; s < 4; ++s) {
            bf8 ap = *(const bf8*)&sB[ln * SBS + 32 * s + 8 * q];
#pragma unroll
            for (int t = 0; t < 4; ++t) {
                bf8 bl = *(const bf8*)&sLut[(16 * t + ln) * KPL + 32 * s + 8 * q];
                eacc[t] = __builtin_amdgcn_mfma_f32_16x16x32_bf16(ap, bl, eacc[t], 0, 0, 0);
            }
        }
        __syncthreads();                               // p reads done before cat writes
        // ---- build cat = [h[dst] | h[src] | e] in sBuf (bf16) ----
#pragma unroll
        for (int i = 0; i < 4; ++i) {
            int idx = i * 64 + lane;
            int row = idx >> 4, seg = idx & 15;
            int dnr = __shfl(dn, row, 64);
            int snr = __shfl(sn, row, 64);
            float4 hd = *(const float4*)&h[(size_t)dnr * 64 + seg * 4];
            float4 hs = *(const float4*)&h[(size_t)snr * 64 + seg * 4];
            uint2 pd; pd.x = pack2(hd.x, hd.y); pd.y = pack2(hd.z, hd.w);
            uint2 ps; ps.x = pack2(hs.x, hs.y); ps.y = pack2(hs.z, hs.w);
            *(uint2*)&sB[row * SBS + seg * 4] = pd;
            *(uint2*)&sB[row * SBS + 64 + seg * 4] = ps;
        }
#pragma unroll
        for (int t = 0; t < 4; ++t)
#pragma unroll
            for (int r = 0; r < 4; ++r)
                sB[(q * 4 + r) * SBS + 128 + ln + 16 * t] = bfs(eacc[t][r]);
        __syncthreads();
        // ---- z = cat @ fcW + fcb ----
        f32x4 zacc[8];
#pragma unroll
        for (int t = 0; t < 8; ++t) zacc[t] = (f32x4){fbias[t], fbias[t], fbias[t], fbias[t]};
#pragma unroll
        for (int s = 0; s < 6; ++s) {
            bf8 ac = *(const bf8*)&sB[ln * SBS + 32 * s + 8 * q];
#pragma unroll
            for (int t = 0; t < 8; ++t) {
                bf8 bw = *(const bf8*)&sFc[(16 * t + ln) * KPF + 32 * s + 8 * q];
                zacc[t] = __builtin_amdgcn_mfma_f32_16x16x32_bf16(ac, bw, zacc[t], 0, 0, 0);
            }
        }
        __syncthreads();                               // cat reads done before z store
        // ---- stats + stage z in sBuf ----
#pragma unroll
        for (int t = 0; t < 8; ++t)
#pragma unroll
            for (int r = 0; r < 4; ++r) {
                float zv = zacc[t][r];
                ss[t] += zv; sq[t] = fmaf(zv, zv, sq[t]);
                sB[(q * 4 + r) * SBS + ln + 16 * t] = bfs(zv);
            }
        __syncthreads();
        // ---- coalesced z writeout: 16 edges x 128 bf16 ----
#pragma unroll
        for (int i = 0; i < 4; ++i) {
            int idx = i * 64 + lane;
            int row = idx >> 4, seg = idx & 15;
            bf8 v = *(const bf8*)&sB[row * SBS + seg * 8];
            *(bf8*)&zo[(size_t)(ebase + row) * 128 + seg * 8] = v;
        }
    }

    // ---- bn1 stats: wave shuffle-reduce -> block LDS reduce -> atomics ----
#pragma unroll
    for (int t = 0; t < 8; ++t) {
        ss[t] += __shfl_xor(ss[t], 16, 64); ss[t] += __shfl_xor(ss[t], 32, 64);
        sq[t] += __shfl_xor(sq[t], 16, 64); sq[t] += __shfl_xor(sq[t], 32, 64);
    }
    __syncthreads();
    float* sred = (float*)&sBuf[0][0];     // 2048 floats used
    if (q == 0) {
#pragma unroll
        for (int t = 0; t < 8; ++t) {
            sred[wave * 128 + ln + 16 * t] = ss[t];
            sred[1024 + wave * 128 + ln + 16 * t] = sq[t];
        }
    }
    __syncthreads();
    if (tid < 256) {
        int base = (tid < 128) ? 0 : 1024;
        int col = tid & 127;
        float s = 0.f;
#pragma unroll
        for (int w = 0; w < 8; ++w) s += sred[base + w * 128 + col];
        atomicAdd(&stats[tid], s);
    }
}

// ------------- bn finalize -------------
__global__ void bn_fin_kernel(const float* __restrict__ stats,
                              const float* __restrict__ g, const float* __restrict__ b,
                              float* __restrict__ bnp, int C, float invN)
{
    int c = threadIdx.x;
    if (c >= C) return;
    float mu = stats[c] * invN;
    float var = stats[C + c] * invN - mu * mu;
    float sc = g[c] * rsqrtf(var + BN_EPS);
    bnp[c] = sc;
    bnp[C + c] = b[c] - mu * sc;
}

// ------------- message + scatter-add (z stored bf16 [E][128]) -------------
__global__ __launch_bounds__(256) void scatter_kernel(
    const unsigned int* __restrict__ z32, const int* __restrict__ ei,
    const float* __restrict__ bnp, float* __restrict__ aggr)
{
    int t = blockIdx.x * 256 + threadIdx.x;           // E*32 threads
    int e = t >> 5, f2 = t & 31;
    unsigned int ua = z32[(size_t)e * 64 + f2];        // cols 2f2, 2f2+1
    unsigned int ub = z32[(size_t)e * 64 + 32 + f2];   // cols 64+2f2, 64+2f2+1
    int f = 2 * f2;
    float zf0 = fmaf(bflo(ua), bnp[f],     bnp[128 + f]);
    float zf1 = fmaf(bfhi(ua), bnp[f + 1], bnp[128 + f + 1]);
    float zc0 = fmaf(bflo(ub), bnp[64 + f],     bnp[192 + f]);
    float zc1 = fmaf(bfhi(ub), bnp[64 + f + 1], bnp[192 + f + 1]);
    float m0 = fmaxf(zf0, 0.f) * fmaxf(zc0, 0.f);
    float m1 = fmaxf(zf1, 0.f) * fmaxf(zc1, 0.f);
    int dst = ei[N_EDGES + e];
    atomicAdd(&aggr[(size_t)dst * 64 + f], m0);
    atomicAdd(&aggr[(size_t)dst * 64 + f + 1], m1);
}

// ------------- column stats over [rows,64] -------------
__global__ __launch_bounds__(256) void colstats64_kernel(
    const float* __restrict__ x, int rows, float* __restrict__ stats)
{
    int f = threadIdx.x & 63, sub = threadIdx.x >> 6;
    float s = 0.f, q = 0.f;
    for (int r = blockIdx.x * 4 + sub; r < rows; r += gridDim.x * 4) {
        float v = x[(size_t)r * 64 + f];
        s += v; q = fmaf(v, v, q);
    }
    __shared__ float ls[4][64], lq[4][64];
    ls[sub][f] = s; lq[sub][f] = q;
    __syncthreads();
    if (sub == 0) {
        s = ls[0][f] + ls[1][f] + ls[2][f] + ls[3][f];
        q = lq[0][f] + lq[1][f] + lq[2][f] + lq[3][f];
        atomicAdd(&stats[f], s);
        atomicAdd(&stats[64 + f], q);
    }
}

// ------------- h_next = relu(h + bn2(aggr)) -------------
__global__ __launch_bounds__(256) void update_kernel(
    const float* __restrict__ h, const float* __restrict__ aggr,
    const float* __restrict__ bnp, float* __restrict__ hout)
{
    int t = blockIdx.x * 256 + threadIdx.x;
    int f = t & 63;
    float v = fmaf(aggr[t], bnp[f], bnp[64 + f]);
    hout[t] = fmaxf(h[t] + v, 0.f);
}

// ------------- pooling -------------
__global__ __launch_bounds__(512, 1) void pool_kernel(
    const float* __restrict__ hbuf, const float* __restrict__ ppW,
    const float* __restrict__ ppb, float* __restrict__ out)
{
    const int b = blockIdx.x;
    const int wave = threadIdx.x >> 6, lane = threadIdx.x & 63;
    float wcol[64];
#pragma unroll
    for (int k = 0; k < 64; ++k) wcol[k] = ppW[k * 64 + lane];
    const float bias = ppb[lane];
    float acc = 0.f;
    for (int r = wave; r < 4 * 400; r += 8) {
        int layer = r / 400, atom = r % 400;
        const float* row = hbuf + ((size_t)layer * N_NODES + (size_t)b * 400 + atom) * 64;
        float v = row[lane];
        float logit = bias;
#pragma unroll
        for (int k = 0; k < 64; ++k) logit = fmaf(__shfl(v, k, 64), wcol[k], logit);
        float m = logit;
#pragma unroll
        for (int o = 32; o >= 1; o >>= 1) m = fmaxf(m, __shfl_xor(m, o, 64));
        float ex = __expf(logit - m);
        float s = ex;
#pragma unroll
        for (int o = 32; o >= 1; o >>= 1) s += __shfl_xor(s, o, 64);
        acc += ex * (1.0f / s);
    }
    __shared__ float sacc[8][64];
    sacc[wave][lane] = acc;
    __syncthreads();
    if (wave == 0) {
        float t = 0.f;
#pragma unroll
        for (int w = 0; w < 8; ++w) t += sacc[w][lane];
        out[(size_t)b * 64 + lane] = t;
    }
}

// ---------------------------------------------------------------------------
extern "C" void kernel_launch(void* const* d_in, const int* in_sizes, int n_in,
                              void* d_out, int out_size, void* d_ws, size_t ws_size,
                              hipStream_t stream)
{
    const float* x        = (const float*)d_in[0];
    const int*   ei       = (const int*)d_in[1];
    const float* ea       = (const float*)d_in[2];
    const float* att      = (const float*)d_in[4];
    const float* embW     = (const float*)d_in[5];
    const float* embB     = (const float*)d_in[6];
    const float* ad_w1    = (const float*)d_in[7];
    const float* ad_b1    = (const float*)d_in[8];
    const float* ad_w2    = (const float*)d_in[9];
    const float* ad_b2    = (const float*)d_in[10];
    const float* ad_alpha = (const float*)d_in[11];
    const float* ad_lut   = (const float*)d_in[12];
    const float* fc_W     = (const float*)d_in[13];
    const float* fc_b     = (const float*)d_in[14];
    const float* bn1_g    = (const float*)d_in[15];
    const float* bn1_b    = (const float*)d_in[16];
    const float* bn2_g    = (const float*)d_in[17];
    const float* bn2_b    = (const float*)d_in[18];
    const float* ppW      = (const float*)d_in[19];
    const float* ppb      = (const float*)d_in[20];
    float* out = (float*)d_out;

    char* ws = (char*)d_ws;
    float* hbuf   = (float*)ws;                                   // 4*N*64 f32 = 52,428,800 B
    short* zU     = (short*)(ws + 52428800);                      // E*128 bf16 = 157,286,400 B
    float* aggr   = (float*)(ws + 52428800 + 157286400);          // N*64 f32   = 13,107,200 B
    float* stats1 = (float*)(ws + 222822400);                     // 256
    float* bnp1   = stats1 + 256;                                 // 256
    float* stats2 = bnp1 + 256;                                   // 128
    float* bnp2   = stats2 + 128;                                 // 128

    embed_kernel<<<512, 256, 0, stream>>>(x, att, embW, embB, hbuf);

    for (int l = 0; l < NCONV; ++l) {
        float* h  = hbuf + (size_t)l * N_NODES * AFL;
        float* hn = h + (size_t)N_NODES * AFL;
        hipMemsetAsync(aggr, 0, (size_t)N_NODES * 64 * 4, stream);
        hipMemsetAsync(stats1, 0, 768 * 4, stream);
        edge_kernel<<<256, 512, 0, stream>>>(
            ea, ei, h,
            ad_w1 + l * BINS, ad_b1 + l * BINS,
            ad_w2 + l * BINS * BINS, ad_b2 + l * BINS,
            ad_alpha + l, ad_lut + l * BINS * NFL,
            fc_W + l * 192 * 128, fc_b + l * 128,
            zU, stats1);
        bn_fin_kernel<<<1, 128, 0, stream>>>(stats1, bn1_g + l * 128, bn1_b + l * 128,
                                             bnp1, 128, 1.0f / N_EDGES);
        scatter_kernel<<<N_EDGES * 32 / 256, 256, 0, stream>>>((const unsigned int*)zU, ei, bnp1, aggr);
        colstats64_kernel<<<256, 256, 0, stream>>>(aggr, N_NODES, stats2);
        bn_fin_kernel<<<1, 128, 0, stream>>>(stats2, bn2_g + l * 64, bn2_b + l * 64,
                                             bnp2, 64, 1.0f / N_NODES);
        update_kernel<<<N_NODES * 64 / 256, 256, 0, stream>>>(h, aggr, bnp2, hn);
    }

    pool_kernel<<<128, 512, 0, stream>>>(hbuf, ppW, ppb, out);
}

// Round 3
// 1801.823 us; speedup vs baseline: 2.9728x; 1.2086x over previous
//
#include <hip/hip_runtime.h>

#define N_NODES 51200
#define N_EDGES 614400
#define ORIG 92
#define AFL 64
#define NFL 64
#define BINS 100
#define NCONV 3
#define BN_EPS 1e-5f
#define NTILES (N_EDGES / 16)   // 38400 edge tiles of 16

typedef __attribute__((ext_vector_type(8))) short bf8;   // 8 bf16 (4 VGPRs)
typedef __attribute__((ext_vector_type(4))) float f32x4;

// ---------- bf16 helpers (bf16 = top 16 bits of fp32, RNE) ----------
__device__ __forceinline__ float bflo(unsigned int u) { return __uint_as_float(u << 16); }
__device__ __forceinline__ float bfhi(unsigned int u) { return __uint_as_float(u & 0xffff0000u); }
__device__ __forceinline__ unsigned int f2bf(float f) {
    unsigned int u = __float_as_uint(f);
    return (u + 0x7fffu + ((u >> 16) & 1u)) >> 16;
}
__device__ __forceinline__ short bfs(float f) { return (short)f2bf(f); }
__device__ __forceinline__ unsigned int pack2(float a, float b) {
    return f2bf(a) | (f2bf(b) << 16);
}

// ---------------------------- embedding ----------------------------
__global__ __launch_bounds__(256) void embed_kernel(
    const float* __restrict__ x, const float* __restrict__ att,
    const float* __restrict__ W, const float* __restrict__ b,
    float* __restrict__ h0)
{
    const int wave = threadIdx.x >> 6, lane = threadIdx.x & 63;
    const int gw = blockIdx.x * 4 + wave;
    const float bv = b[lane];
    for (int n = gw; n < N_NODES; n += gridDim.x * 4) {
        const float* xr = x + (size_t)n * ORIG;
        float acc = bv;
        for (int k = 0; k < ORIG; ++k)
            acc = fmaf(xr[k] * att[k], W[k * AFL + lane], acc);
        h0[(size_t)n * AFL + lane] = acc;
    }
}

// ---------------------------- MFMA edge kernel ----------------------------
// wave = one 16-edge tile per iteration. sBuf is WAVE-PRIVATE -> no per-tile
// __syncthreads(); within-wave LDS ordering is guaranteed (in-order DS +
// compiler lgkmcnt). Only the weight-staging barrier and the final stats
// reduction barriers remain.
#define KP2 136   // W2t row stride (K=128 padded)
#define KPL 136   // lutT
#define KPF 200   // fcT  (K=192 padded)
#define SBS 200   // per-wave sBuf row stride (16 rows)

__global__ __launch_bounds__(512, 1) void edge_kernel(
    const float* __restrict__ ea, const int* __restrict__ ei,
    const float* __restrict__ h,
    const float* __restrict__ w1, const float* __restrict__ b1,
    const float* __restrict__ w2, const float* __restrict__ b2,
    const float* __restrict__ alpha_p, const float* __restrict__ lut,
    const float* __restrict__ fcW, const float* __restrict__ fcb,
    short* __restrict__ zo, float* __restrict__ stats)
{
    __shared__ short sW2[112 * KP2];      // 30464 B
    __shared__ short sLut[64 * KPL];      // 17408 B
    __shared__ short sFc[128 * KPF];      // 51200 B
    __shared__ short sBuf[8][16 * SBS];   // 51200 B   total 150272 B

    const int tid = threadIdx.x;
    // ---- stage weights transposed to [N][K] bf16 ----
    for (int i = tid; i < 112 * 128; i += 512) {
        int n = i >> 7, k = i & 127;
        float v = (n < BINS && k < BINS) ? w2[k * BINS + n] : 0.f;
        sW2[n * KP2 + k] = bfs(v);
    }
    for (int i = tid; i < 64 * 128; i += 512) {
        int f = i >> 7, k = i & 127;
        float v = (k < BINS) ? lut[k * NFL + f] : 0.f;
        sLut[f * KPL + k] = bfs(v);
    }
    for (int i = tid; i < 128 * 192; i += 512) {
        int n = i / 192, k = i - n * 192;
        sFc[n * KPF + k] = bfs(fcW[k * 128 + n]);
    }
    __syncthreads();

    const int wave = tid >> 6, lane = tid & 63;
    const int ln = lane & 15, q = lane >> 4;
    short* sB = &sBuf[wave][0];
    const float alpha = alpha_p[0];

    // per-lane constants
    float w1r[32], b1r[32];                 // A-layout v2: k = 32s + 8q + j
#pragma unroll
    for (int s = 0; s < 4; ++s)
#pragma unroll
        for (int j = 0; j < 8; ++j) {
            int k = 32 * s + 8 * q + j;
            bool v = k < BINS;
            w1r[s * 8 + j] = v ? w1[k] : 0.f;
            b1r[s * 8 + j] = v ? b1[k] : 0.f;
        }
    float w1c[7], b1c[7], b2c[7];           // C-layout col = ln + 16t
#pragma unroll
    for (int t = 0; t < 7; ++t) {
        int c = ln + 16 * t;
        bool v = c < BINS;
        w1c[t] = v ? w1[c] : 0.f;
        b1c[t] = v ? b1[c] : 0.f;
        b2c[t] = v ? b2[c] : 0.f;
    }
    float fbias[8];
#pragma unroll
    for (int t = 0; t < 8; ++t) fbias[t] = fcb[ln + 16 * t];

    float ss[8], sq[8];
#pragma unroll
    for (int t = 0; t < 8; ++t) { ss[t] = 0.f; sq[t] = 0.f; }

    for (int tile = blockIdx.x * 8 + wave; tile < NTILES; tile += 2048) {
        const int ebase = tile * 16;
        const float av = ea[ebase + ln];
        const int sn = ei[ebase + ln];
        const int dn = ei[N_EDGES + ebase + ln];

        // ---- v3 = v2@W2 + b2 + alpha*v2 ----
        f32x4 acc[7];
#pragma unroll
        for (int t = 0; t < 7; ++t) {
#pragma unroll
            for (int r = 0; r < 4; ++r) {
                float ar = __shfl(av, q * 4 + r, 64);
                float v2c = fmaf(ar, w1c[t], b1c[t]);
                v2c = v2c > 0.f ? v2c : 0.01f * v2c;
                acc[t][r] = fmaf(alpha, v2c, b2c[t]);
            }
        }
#pragma unroll
        for (int s = 0; s < 4; ++s) {
            bf8 a2;
#pragma unroll
            for (int j = 0; j < 8; ++j) {
                float v = fmaf(av, w1r[s * 8 + j], b1r[s * 8 + j]);
                v = v > 0.f ? v : 0.01f * v;
                a2[j] = bfs(v);
            }
#pragma unroll
            for (int t = 0; t < 7; ++t) {
                bf8 bw = *(const bf8*)&sW2[(16 * t + ln) * KP2 + 32 * s + 8 * q];
                acc[t] = __builtin_amdgcn_mfma_f32_16x16x32_bf16(a2, bw, acc[t], 0, 0, 0);
            }
        }
        // ---- softmax over 100 bins (C layout; row-group = 16 lanes) ----
#pragma unroll
        for (int r = 0; r < 4; ++r) {
            float m = -3.4e38f;
#pragma unroll
            for (int t = 0; t < 7; ++t)
                if (t < 6 || ln < 4) m = fmaxf(m, acc[t][r]);
#pragma unroll
            for (int o = 8; o >= 1; o >>= 1) m = fmaxf(m, __shfl_xor(m, o, 16));
            float ev[7], s = 0.f;
#pragma unroll
            for (int t = 0; t < 7; ++t) {
                ev[t] = (t < 6 || ln < 4) ? __expf(acc[t][r] - m) : 0.f;
                s += ev[t];
            }
#pragma unroll
            for (int o = 8; o >= 1; o >>= 1) s += __shfl_xor(s, o, 16);
            float inv = 1.0f / s;
#pragma unroll
            for (int t = 0; t < 7; ++t)
                if (t < 6 || ln < 4) sB[(q * 4 + r) * SBS + ln + 16 * t] = bfs(ev[t] * inv);
        }
        // zero-pad p cols [100,128)
        for (int i = lane; i < 16 * 28; i += 64) {
            int row = i / 28, c = 100 + (i - row * 28);
            sB[row * SBS + c] = 0;
        }
        // ---- e = p @ lut ----
        f32x4 eacc[4];
#pragma unroll
        for (int t = 0; t < 4; ++t) eacc[t] = (f32x4){0.f, 0.f, 0.f, 0.f};
#pragma unroll
        for (int s = 0; s < 4; ++s) {
            bf8 ap = *(const bf8*)&sB[ln * SBS + 32 * s + 8 * q];
#pragma unroll
            for (int t = 0; t < 4; ++t) {
                bf8 bl = *(const bf8*)&sLut[(16 * t + ln) * KPL + 32 * s + 8 * q];
                eacc[t] = __builtin_amdgcn_mfma_f32_16x16x32_bf16(ap, bl, eacc[t], 0, 0, 0);
            }
        }
        // ---- build cat = [h[dst] | h[src] | e] in sBuf (bf16) ----
#pragma unroll
        for (int i = 0; i < 4; ++i) {
            int idx = i * 64 + lane;
            int row = idx >> 4, seg = idx & 15;
            int dnr = __shfl(dn, row, 64);
            int snr = __shfl(sn, row, 64);
            float4 hd = *(const float4*)&h[(size_t)dnr * 64 + seg * 4];
            float4 hs = *(const float4*)&h[(size_t)snr * 64 + seg * 4];
            uint2 pd; pd.x = pack2(hd.x, hd.y); pd.y = pack2(hd.z, hd.w);
            uint2 ps; ps.x = pack2(hs.x, hs.y); ps.y = pack2(hs.z, hs.w);
            *(uint2*)&sB[row * SBS + seg * 4] = pd;
            *(uint2*)&sB[row * SBS + 64 + seg * 4] = ps;
        }
#pragma unroll
        for (int t = 0; t < 4; ++t)
#pragma unroll
            for (int r = 0; r < 4; ++r)
                sB[(q * 4 + r) * SBS + 128 + ln + 16 * t] = bfs(eacc[t][r]);
        // ---- z = cat @ fcW + fcb ----
        f32x4 zacc[8];
#pragma unroll
        for (int t = 0; t < 8; ++t) zacc[t] = (f32x4){fbias[t], fbias[t], fbias[t], fbias[t]};
#pragma unroll
        for (int s = 0; s < 6; ++s) {
            bf8 ac = *(const bf8*)&sB[ln * SBS + 32 * s + 8 * q];
#pragma unroll
            for (int t = 0; t < 8; ++t) {
                bf8 bw = *(const bf8*)&sFc[(16 * t + ln) * KPF + 32 * s + 8 * q];
                zacc[t] = __builtin_amdgcn_mfma_f32_16x16x32_bf16(ac, bw, zacc[t], 0, 0, 0);
            }
        }
        // ---- stats + stage z in sBuf ----
#pragma unroll
        for (int t = 0; t < 8; ++t)
#pragma unroll
            for (int r = 0; r < 4; ++r) {
                float zv = zacc[t][r];
                ss[t] += zv; sq[t] = fmaf(zv, zv, sq[t]);
                sB[(q * 4 + r) * SBS + ln + 16 * t] = bfs(zv);
            }
        // ---- coalesced z writeout: 16 edges x 128 bf16 ----
#pragma unroll
        for (int i = 0; i < 4; ++i) {
            int idx = i * 64 + lane;
            int row = idx >> 4, seg = idx & 15;
            bf8 v = *(const bf8*)&sB[row * SBS + seg * 8];
            *(bf8*)&zo[(size_t)(ebase + row) * 128 + seg * 8] = v;
        }
    }

    // ---- bn1 stats: wave shuffle-reduce -> block LDS reduce -> atomics ----
#pragma unroll
    for (int t = 0; t < 8; ++t) {
        ss[t] += __shfl_xor(ss[t], 16, 64); ss[t] += __shfl_xor(ss[t], 32, 64);
        sq[t] += __shfl_xor(sq[t], 16, 64); sq[t] += __shfl_xor(sq[t], 32, 64);
    }
    __syncthreads();
    float* sred = (float*)&sBuf[0][0];     // 2048 floats used
    if (q == 0) {
#pragma unroll
        for (int t = 0; t < 8; ++t) {
            sred[wave * 128 + ln + 16 * t] = ss[t];
            sred[1024 + wave * 128 + ln + 16 * t] = sq[t];
        }
    }
    __syncthreads();
    if (tid < 256) {
        int base = (tid < 128) ? 0 : 1024;
        int col = tid & 127;
        float s = 0.f;
#pragma unroll
        for (int w = 0; w < 8; ++w) s += sred[base + w * 128 + col];
        atomicAdd(&stats[tid], s);
    }
}

// ------------- bn finalize -------------
__global__ void bn_fin_kernel(const float* __restrict__ stats,
                              const float* __restrict__ g, const float* __restrict__ b,
                              float* __restrict__ bnp, int C, float invN)
{
    int c = threadIdx.x;
    if (c >= C) return;
    float mu = stats[c] * invN;
    float var = stats[C + c] * invN - mu * mu;
    float sc = g[c] * rsqrtf(var + BN_EPS);
    bnp[c] = sc;
    bnp[C + c] = b[c] - mu * sc;
}

// ------------- message + scatter-add (z stored bf16 [E][128]) -------------
__global__ __launch_bounds__(256) void scatter_kernel(
    const unsigned int* __restrict__ z32, const int* __restrict__ ei,
    const float* __restrict__ bnp, float* __restrict__ aggr)
{
    int t = blockIdx.x * 256 + threadIdx.x;           // E*32 threads
    int e = t >> 5, f2 = t & 31;
    unsigned int ua = z32[(size_t)e * 64 + f2];        // cols 2f2, 2f2+1
    unsigned int ub = z32[(size_t)e * 64 + 32 + f2];   // cols 64+2f2, 64+2f2+1
    int f = 2 * f2;
    float zf0 = fmaf(bflo(ua), bnp[f],     bnp[128 + f]);
    float zf1 = fmaf(bfhi(ua), bnp[f + 1], bnp[128 + f + 1]);
    float zc0 = fmaf(bflo(ub), bnp[64 + f],     bnp[192 + f]);
    float zc1 = fmaf(bfhi(ub), bnp[64 + f + 1], bnp[192 + f + 1]);
    float m0 = fmaxf(zf0, 0.f) * fmaxf(zc0, 0.f);
    float m1 = fmaxf(zf1, 0.f) * fmaxf(zc1, 0.f);
    int dst = ei[N_EDGES + e];
    atomicAdd(&aggr[(size_t)dst * 64 + f], m0);
    atomicAdd(&aggr[(size_t)dst * 64 + f + 1], m1);
}

// ------------- column stats over [rows,64] -------------
__global__ __launch_bounds__(256) void colstats64_kernel(
    const float* __restrict__ x, int rows, float* __restrict__ stats)
{
    int f = threadIdx.x & 63, sub = threadIdx.x >> 6;
    float s = 0.f, q = 0.f;
    for (int r = blockIdx.x * 4 + sub; r < rows; r += gridDim.x * 4) {
        float v = x[(size_t)r * 64 + f];
        s += v; q = fmaf(v, v, q);
    }
    __shared__ float ls[4][64], lq[4][64];
    ls[sub][f] = s; lq[sub][f] = q;
    __syncthreads();
    if (sub == 0) {
        s = ls[0][f] + ls[1][f] + ls[2][f] + ls[3][f];
        q = lq[0][f] + lq[1][f] + lq[2][f] + lq[3][f];
        atomicAdd(&stats[f], s);
        atomicAdd(&stats[64 + f], q);
    }
}

// ------------- h_next = relu(h + bn2(aggr)) -------------
__global__ __launch_bounds__(256) void update_kernel(
    const float* __restrict__ h, const float* __restrict__ aggr,
    const float* __restrict__ bnp, float* __restrict__ hout)
{
    int t = blockIdx.x * 256 + threadIdx.x;
    int f = t & 63;
    float v = fmaf(aggr[t], bnp[f], bnp[64 + f]);
    hout[t] = fmaxf(h[t] + v, 0.f);
}

// ------------- pooling: block = (layer, batch), 4 waves, 2 rows/wave/iter -------------
__global__ __launch_bounds__(256) void pool_kernel(
    const float* __restrict__ hbuf, const float* __restrict__ ppW,
    const float* __restrict__ ppb, float* __restrict__ out)
{
    const int l = blockIdx.x >> 7, b = blockIdx.x & 127;
    const int wave = threadIdx.x >> 6, lane = threadIdx.x & 63;
    float wcol[64];
#pragma unroll
    for (int k = 0; k < 64; ++k) wcol[k] = ppW[k * 64 + lane];
    const float bias = ppb[lane];
    const float* base = hbuf + ((size_t)l * N_NODES + (size_t)b * 400) * 64;
    __shared__ float srow[4][2][64];
    __shared__ float sacc[4][64];
    float acc = 0.f;
    for (int r = wave * 2; r < 400; r += 8) {
        srow[wave][0][lane] = base[(size_t)r * 64 + lane];
        srow[wave][1][lane] = base[(size_t)r * 64 + 64 + lane];
        float lg0 = bias, lg1 = bias;
#pragma unroll
        for (int k4 = 0; k4 < 64; k4 += 4) {
            float4 a = *(const float4*)&srow[wave][0][k4];
            float4 c = *(const float4*)&srow[wave][1][k4];
            lg0 = fmaf(a.x, wcol[k4 + 0], lg0); lg1 = fmaf(c.x, wcol[k4 + 0], lg1);
            lg0 = fmaf(a.y, wcol[k4 + 1], lg0); lg1 = fmaf(c.y, wcol[k4 + 1], lg1);
            lg0 = fmaf(a.z, wcol[k4 + 2], lg0); lg1 = fmaf(c.z, wcol[k4 + 2], lg1);
            lg0 = fmaf(a.w, wcol[k4 + 3], lg0); lg1 = fmaf(c.w, wcol[k4 + 3], lg1);
        }
        float m0 = lg0, m1 = lg1;
#pragma unroll
        for (int o = 32; o >= 1; o >>= 1) {
            m0 = fmaxf(m0, __shfl_xor(m0, o, 64));
            m1 = fmaxf(m1, __shfl_xor(m1, o, 64));
        }
        float e0 = __expf(lg0 - m0), e1 = __expf(lg1 - m1);
        float s0 = e0, s1 = e1;
#pragma unroll
        for (int o = 32; o >= 1; o >>= 1) {
            s0 += __shfl_xor(s0, o, 64);
            s1 += __shfl_xor(s1, o, 64);
        }
        acc += e0 * (1.0f / s0) + e1 * (1.0f / s1);
    }
    sacc[wave][lane] = acc;
    __syncthreads();
    if (wave == 0) {
        float t = sacc[0][lane] + sacc[1][lane] + sacc[2][lane] + sacc[3][lane];
        atomicAdd(&out[(size_t)b * 64 + lane], t);
    }
}

// ---------------------------------------------------------------------------
extern "C" void kernel_launch(void* const* d_in, const int* in_sizes, int n_in,
                              void* d_out, int out_size, void* d_ws, size_t ws_size,
                              hipStream_t stream)
{
    const float* x        = (const float*)d_in[0];
    const int*   ei       = (const int*)d_in[1];
    const float* ea       = (const float*)d_in[2];
    const float* att      = (const float*)d_in[4];
    const float* embW     = (const float*)d_in[5];
    const float* embB     = (const float*)d_in[6];
    const float* ad_w1    = (const float*)d_in[7];
    const float* ad_b1    = (const float*)d_in[8];
    const float* ad_w2    = (const float*)d_in[9];
    const float* ad_b2    = (const float*)d_in[10];
    const float* ad_alpha = (const float*)d_in[11];
    const float* ad_lut   = (const float*)d_in[12];
    const float* fc_W     = (const float*)d_in[13];
    const float* fc_b     = (const float*)d_in[14];
    const float* bn1_g    = (const float*)d_in[15];
    const float* bn1_b    = (const float*)d_in[16];
    const float* bn2_g    = (const float*)d_in[17];
    const float* bn2_b    = (const float*)d_in[18];
    const float* ppW      = (const float*)d_in[19];
    const float* ppb      = (const float*)d_in[20];
    float* out = (float*)d_out;

    char* ws = (char*)d_ws;
    float* hbuf   = (float*)ws;                                   // 4*N*64 f32 = 52,428,800 B
    short* zU     = (short*)(ws + 52428800);                      // E*128 bf16 = 157,286,400 B
    float* aggr   = (float*)(ws + 52428800 + 157286400);          // N*64 f32   = 13,107,200 B
    float* stats1 = (float*)(ws + 222822400);                     // 256
    float* bnp1   = stats1 + 256;                                 // 256
    float* stats2 = bnp1 + 256;                                   // 128
    float* bnp2   = stats2 + 128;                                 // 128

    hipMemsetAsync(out, 0, 128 * 64 * sizeof(float), stream);
    embed_kernel<<<512, 256, 0, stream>>>(x, att, embW, embB, hbuf);

    for (int l = 0; l < NCONV; ++l) {
        float* h  = hbuf + (size_t)l * N_NODES * AFL;
        float* hn = h + (size_t)N_NODES * AFL;
        hipMemsetAsync(aggr, 0, (size_t)N_NODES * 64 * 4, stream);
        hipMemsetAsync(stats1, 0, 768 * 4, stream);
        edge_kernel<<<256, 512, 0, stream>>>(
            ea, ei, h,
            ad_w1 + l * BINS, ad_b1 + l * BINS,
            ad_w2 + l * BINS * BINS, ad_b2 + l * BINS,
            ad_alpha + l, ad_lut + l * BINS * NFL,
            fc_W + l * 192 * 128, fc_b + l * 128,
            zU, stats1);
        bn_fin_kernel<<<1, 128, 0, stream>>>(stats1, bn1_g + l * 128, bn1_b + l * 128,
                                             bnp1, 128, 1.0f / N_EDGES);
        scatter_kernel<<<N_EDGES * 32 / 256, 256, 0, stream>>>((const unsigned int*)zU, ei, bnp1, aggr);
        colstats64_kernel<<<256, 256, 0, stream>>>(aggr, N_NODES, stats2);
        bn_fin_kernel<<<1, 128, 0, stream>>>(stats2, bn2_g + l * 64, bn2_b + l * 64,
                                             bnp2, 64, 1.0f / N_NODES);
        update_kernel<<<N_NODES * 64 / 256, 256, 0, stream>>>(h, aggr, bnp2, hn);
    }

    pool_kernel<<<512, 256, 0, stream>>>(hbuf, ppW, ppb, out);
}

// Round 4
// 1486.398 us; speedup vs baseline: 3.6037x; 1.2122x over previous
//
#include <hip/hip_runtime.h>

#define N_NODES 51200
#define N_EDGES 614400
#define ORIG 92
#define AFL 64
#define NFL 64
#define BINS 100
#define NCONV 3
#define BN_EPS 1e-5f
#define NTILES (N_EDGES / 16)   // 38400 edge tiles of 16

typedef __attribute__((ext_vector_type(8))) short bf8;   // 8 bf16 (4 VGPRs)
typedef __attribute__((ext_vector_type(4))) float f32x4;

// ---------- bf16 helpers (bf16 = top 16 bits of fp32, RNE) ----------
__device__ __forceinline__ float bflo(unsigned int u) { return __uint_as_float(u << 16); }
__device__ __forceinline__ float bfhi(unsigned int u) { return __uint_as_float(u & 0xffff0000u); }
__device__ __forceinline__ unsigned int f2bf(float f) {
    unsigned int u = __float_as_uint(f);
    return (u + 0x7fffu + ((u >> 16) & 1u)) >> 16;
}
__device__ __forceinline__ short bfs(float f) { return (short)f2bf(f); }
__device__ __forceinline__ unsigned int pack2(float a, float b) {
    return f2bf(a) | (f2bf(b) << 16);
}

// ---------------------------- CSR build (once per launch) ----------------------------
__global__ __launch_bounds__(256) void hist_kernel(const int* __restrict__ ei,
                                                   int* __restrict__ cnt)
{
    int e = blockIdx.x * 256 + threadIdx.x;
    atomicAdd(&cnt[ei[N_EDGES + e]], 1);
}

// one block, 1024 threads, 50 elements each; cnt aliases cursor (overwritten in place)
__global__ __launch_bounds__(1024) void scan_kernel(int* __restrict__ cnt_cursor,
                                                    int* __restrict__ rowptr)
{
    __shared__ int part[1024];
    const int t = threadIdx.x;
    const int base = t * 50;
    int s = 0;
#pragma unroll 10
    for (int i = 0; i < 50; ++i) s += cnt_cursor[base + i];
    part[t] = s;
    __syncthreads();
    for (int off = 1; off < 1024; off <<= 1) {
        int v = (t >= off) ? part[t - off] : 0;
        __syncthreads();
        part[t] += v;
        __syncthreads();
    }
    int run = (t == 0) ? 0 : part[t - 1];
    for (int i = 0; i < 50; ++i) {
        int c = cnt_cursor[base + i];
        rowptr[base + i] = run;
        cnt_cursor[base + i] = run;   // cursor init
        run += c;
    }
    if (t == 1023) rowptr[N_NODES] = run;
}

__global__ __launch_bounds__(256) void permbuild_kernel(const int* __restrict__ ei,
                                                        int* __restrict__ cursor,
                                                        int* __restrict__ perm)
{
    int e = blockIdx.x * 256 + threadIdx.x;
    int d = ei[N_EDGES + e];
    int pos = atomicAdd(&cursor[d], 1);
    perm[pos] = e;
}

// ---------------------------- embedding ----------------------------
__global__ __launch_bounds__(256) void embed_kernel(
    const float* __restrict__ x, const float* __restrict__ att,
    const float* __restrict__ W, const float* __restrict__ b,
    float* __restrict__ h0)
{
    const int wave = threadIdx.x >> 6, lane = threadIdx.x & 63;
    const int gw = blockIdx.x * 4 + wave;
    const float bv = b[lane];
    for (int n = gw; n < N_NODES; n += gridDim.x * 4) {
        const float* xr = x + (size_t)n * ORIG;
        float acc = bv;
        for (int k = 0; k < ORIG; ++k)
            acc = fmaf(xr[k] * att[k], W[k * AFL + lane], acc);
        h0[(size_t)n * AFL + lane] = acc;
    }
}

// ---------------------------- MFMA edge kernel ----------------------------
// wave = one 16-edge tile (dst-sorted via perm). sBuf wave-private -> no per-tile
// barriers. One-tile-ahead software pipeline: indices then h-rows prefetched into
// a register double buffer (occupancy is LDS-capped, VGPRs free).
#define KP2 136   // W2t row stride (K=128 padded)
#define KPL 136   // lutT
#define KPF 200   // fcT  (K=192 padded)
#define SBS 200   // per-wave sBuf row stride (16 rows)

__global__ __launch_bounds__(512, 1) void edge_kernel(
    const float* __restrict__ ea, const int* __restrict__ ei,
    const int* __restrict__ perm,
    const float* __restrict__ h,
    const float* __restrict__ w1, const float* __restrict__ b1,
    const float* __restrict__ w2, const float* __restrict__ b2,
    const float* __restrict__ alpha_p, const float* __restrict__ lut,
    const float* __restrict__ fcW, const float* __restrict__ fcb,
    short* __restrict__ zo, float* __restrict__ stats)
{
    __shared__ short sW2[112 * KP2];      // 30464 B
    __shared__ short sLut[64 * KPL];      // 17408 B
    __shared__ short sFc[128 * KPF];      // 51200 B
    __shared__ short sBuf[8][16 * SBS];   // 51200 B   total 150272 B

    const int tid = threadIdx.x;
    for (int i = tid; i < 112 * 128; i += 512) {
        int n = i >> 7, k = i & 127;
        float v = (n < BINS && k < BINS) ? w2[k * BINS + n] : 0.f;
        sW2[n * KP2 + k] = bfs(v);
    }
    for (int i = tid; i < 64 * 128; i += 512) {
        int f = i >> 7, k = i & 127;
        float v = (k < BINS) ? lut[k * NFL + f] : 0.f;
        sLut[f * KPL + k] = bfs(v);
    }
    for (int i = tid; i < 128 * 192; i += 512) {
        int n = i / 192, k = i - n * 192;
        sFc[n * KPF + k] = bfs(fcW[k * 128 + n]);
    }
    __syncthreads();

    const int wave = tid >> 6, lane = tid & 63;
    const int ln = lane & 15, q = lane >> 4;
    short* sB = &sBuf[wave][0];
    const float alpha = alpha_p[0];

    float w1r[32], b1r[32];                 // A-layout v2: k = 32s + 8q + j
#pragma unroll
    for (int s = 0; s < 4; ++s)
#pragma unroll
        for (int j = 0; j < 8; ++j) {
            int k = 32 * s + 8 * q + j;
            bool v = k < BINS;
            w1r[s * 8 + j] = v ? w1[k] : 0.f;
            b1r[s * 8 + j] = v ? b1[k] : 0.f;
        }
    float w1c[7], b1c[7], b2c[7];           // C-layout col = ln + 16t
#pragma unroll
    for (int t = 0; t < 7; ++t) {
        int c = ln + 16 * t;
        bool v = c < BINS;
        w1c[t] = v ? w1[c] : 0.f;
        b1c[t] = v ? b1[c] : 0.f;
        b2c[t] = v ? b2[c] : 0.f;
    }
    float fbias[8];
#pragma unroll
    for (int t = 0; t < 8; ++t) fbias[t] = fcb[ln + 16 * t];

    float ss[8], sq[8];
#pragma unroll
    for (int t = 0; t < 8; ++t) { ss[t] = 0.f; sq[t] = 0.f; }

    int tile = blockIdx.x * 8 + wave;
    // ---- prologue prefetch: tile indices + h rows ----
    float avC = 0.f; int snC = 0, dnC = 0;
    float4 hdC[4], hsC[4];
    if (tile < NTILES) {
        int e0 = perm[tile * 16 + ln];
        avC = ea[e0]; snC = ei[e0]; dnC = ei[N_EDGES + e0];
#pragma unroll
        for (int i = 0; i < 4; ++i) {
            int idx = i * 64 + lane;
            int row = idx >> 4, seg = idx & 15;
            int dnr = __shfl(dnC, row, 64);
            int snr = __shfl(snC, row, 64);
            hdC[i] = *(const float4*)&h[(size_t)dnr * 64 + seg * 4];
            hsC[i] = *(const float4*)&h[(size_t)snr * 64 + seg * 4];
        }
    }

    for (; tile < NTILES; tile += 2048) {
        const int ebase = tile * 16;
        // ---- issue next tile's index loads ----
        const int tn = tile + 2048;
        const int tsafe = (tn < NTILES) ? tn : tile;
        int eN_ = perm[tsafe * 16 + ln];
        float avN = ea[eN_];
        int snN = ei[eN_];
        int dnN = ei[N_EDGES + eN_];

        // ---- v3 = v2@W2 + b2 + alpha*v2 (uses current av) ----
        f32x4 acc[7];
#pragma unroll
        for (int t = 0; t < 7; ++t) {
#pragma unroll
            for (int r = 0; r < 4; ++r) {
                float ar = __shfl(avC, q * 4 + r, 64);
                float v2c = fmaf(ar, w1c[t], b1c[t]);
                v2c = v2c > 0.f ? v2c : 0.01f * v2c;
                acc[t][r] = fmaf(alpha, v2c, b2c[t]);
            }
        }
#pragma unroll
        for (int s = 0; s < 4; ++s) {
            bf8 a2;
#pragma unroll
            for (int j = 0; j < 8; ++j) {
                float v = fmaf(avC, w1r[s * 8 + j], b1r[s * 8 + j]);
                v = v > 0.f ? v : 0.01f * v;
                a2[j] = bfs(v);
            }
#pragma unroll
            for (int t = 0; t < 7; ++t) {
                bf8 bw = *(const bf8*)&sW2[(16 * t + ln) * KP2 + 32 * s + 8 * q];
                acc[t] = __builtin_amdgcn_mfma_f32_16x16x32_bf16(a2, bw, acc[t], 0, 0, 0);
            }
        }

        // ---- issue next tile's h gathers (snN/dnN have landed during v3) ----
        float4 hdN[4], hsN[4];
#pragma unroll
        for (int i = 0; i < 4; ++i) {
            int idx = i * 64 + lane;
            int row = idx >> 4, seg = idx & 15;
            int dnr = __shfl(dnN, row, 64);
            int snr = __shfl(snN, row, 64);
            hdN[i] = *(const float4*)&h[(size_t)dnr * 64 + seg * 4];
            hsN[i] = *(const float4*)&h[(size_t)snr * 64 + seg * 4];
        }

        // ---- softmax over 100 bins (C layout; row-group = 16 lanes) ----
#pragma unroll
        for (int r = 0; r < 4; ++r) {
            float m = -3.4e38f;
#pragma unroll
            for (int t = 0; t < 7; ++t)
                if (t < 6 || ln < 4) m = fmaxf(m, acc[t][r]);
#pragma unroll
            for (int o = 8; o >= 1; o >>= 1) m = fmaxf(m, __shfl_xor(m, o, 16));
            float ev[7], s = 0.f;
#pragma unroll
            for (int t = 0; t < 7; ++t) {
                ev[t] = (t < 6 || ln < 4) ? __expf(acc[t][r] - m) : 0.f;
                s += ev[t];
            }
#pragma unroll
            for (int o = 8; o >= 1; o >>= 1) s += __shfl_xor(s, o, 16);
            float inv = 1.0f / s;
#pragma unroll
            for (int t = 0; t < 7; ++t)
                if (t < 6 || ln < 4) sB[(q * 4 + r) * SBS + ln + 16 * t] = bfs(ev[t] * inv);
        }
        for (int i = lane; i < 16 * 28; i += 64) {
            int row = i / 28, c = 100 + (i - row * 28);
            sB[row * SBS + c] = 0;
        }
        // ---- e = p @ lut ----
        f32x4 eacc[4];
#pragma unroll
        for (int t = 0; t < 4; ++t) eacc[t] = (f32x4){0.f, 0.f, 0.f, 0.f};
#pragma unroll
        for (int s = 0; s < 4; ++s) {
            bf8 ap = *(const bf8*)&sB[ln * SBS + 32 * s + 8 * q];
#pragma unroll
            for (int t = 0; t < 4; ++t) {
                bf8 bl = *(const bf8*)&sLut[(16 * t + ln) * KPL + 32 * s + 8 * q];
                eacc[t] = __builtin_amdgcn_mfma_f32_16x16x32_bf16(ap, bl, eacc[t], 0, 0, 0);
            }
        }
        // ---- build cat = [h[dst] | h[src] | e] from CURRENT h regs ----
#pragma unroll
        for (int i = 0; i < 4; ++i) {
            int idx = i * 64 + lane;
            int row = idx >> 4, seg = idx & 15;
            uint2 pd; pd.x = pack2(hdC[i].x, hdC[i].y); pd.y = pack2(hdC[i].z, hdC[i].w);
            uint2 ps; ps.x = pack2(hsC[i].x, hsC[i].y); ps.y = pack2(hsC[i].z, hsC[i].w);
            *(uint2*)&sB[row * SBS + seg * 4] = pd;
            *(uint2*)&sB[row * SBS + 64 + seg * 4] = ps;
        }
#pragma unroll
        for (int t = 0; t < 4; ++t)
#pragma unroll
            for (int r = 0; r < 4; ++r)
                sB[(q * 4 + r) * SBS + 128 + ln + 16 * t] = bfs(eacc[t][r]);
        // ---- z = cat @ fcW + fcb ----
        f32x4 zacc[8];
#pragma unroll
        for (int t = 0; t < 8; ++t) zacc[t] = (f32x4){fbias[t], fbias[t], fbias[t], fbias[t]};
#pragma unroll
        for (int s = 0; s < 6; ++s) {
            bf8 ac = *(const bf8*)&sB[ln * SBS + 32 * s + 8 * q];
#pragma unroll
            for (int t = 0; t < 8; ++t) {
                bf8 bw = *(const bf8*)&sFc[(16 * t + ln) * KPF + 32 * s + 8 * q];
                zacc[t] = __builtin_amdgcn_mfma_f32_16x16x32_bf16(ac, bw, zacc[t], 0, 0, 0);
            }
        }
        // ---- stats + stage z ----
#pragma unroll
        for (int t = 0; t < 8; ++t)
#pragma unroll
            for (int r = 0; r < 4; ++r) {
                float zv = zacc[t][r];
                ss[t] += zv; sq[t] = fmaf(zv, zv, sq[t]);
                sB[(q * 4 + r) * SBS + ln + 16 * t] = bfs(zv);
            }
        // ---- coalesced z writeout (sorted index space) ----
#pragma unroll
        for (int i = 0; i < 4; ++i) {
            int idx = i * 64 + lane;
            int row = idx >> 4, seg = idx & 15;
            bf8 v = *(const bf8*)&sB[row * SBS + seg * 8];
            *(bf8*)&zo[(size_t)(ebase + row) * 128 + seg * 8] = v;
        }
        // ---- rotate prefetch buffers ----
        avC = avN; snC = snN; dnC = dnN;
#pragma unroll
        for (int i = 0; i < 4; ++i) { hdC[i] = hdN[i]; hsC[i] = hsN[i]; }
    }

    // ---- bn1 stats reduction ----
#pragma unroll
    for (int t = 0; t < 8; ++t) {
        ss[t] += __shfl_xor(ss[t], 16, 64); ss[t] += __shfl_xor(ss[t], 32, 64);
        sq[t] += __shfl_xor(sq[t], 16, 64); sq[t] += __shfl_xor(sq[t], 32, 64);
    }
    __syncthreads();
    float* sred = (float*)&sBuf[0][0];
    if (q == 0) {
#pragma unroll
        for (int t = 0; t < 8; ++t) {
            sred[wave * 128 + ln + 16 * t] = ss[t];
            sred[1024 + wave * 128 + ln + 16 * t] = sq[t];
        }
    }
    __syncthreads();
    if (tid < 256) {
        int base = (tid < 128) ? 0 : 1024;
        int col = tid & 127;
        float s = 0.f;
#pragma unroll
        for (int w = 0; w < 8; ++w) s += sred[base + w * 128 + col];
        atomicAdd(&stats[tid], s);
    }
}

// ------------- bn finalize -------------
__global__ void bn_fin_kernel(const float* __restrict__ stats,
                              const float* __restrict__ g, const float* __restrict__ b,
                              float* __restrict__ bnp, int C, float invN)
{
    int c = threadIdx.x;
    if (c >= C) return;
    float mu = stats[c] * invN;
    float var = stats[C + c] * invN - mu * mu;
    float sc = g[c] * rsqrtf(var + BN_EPS);
    bnp[c] = sc;
    bnp[C + c] = b[c] - mu * sc;
}

// ------------- CSR aggregate: wave per node, zero atomics -------------
__global__ __launch_bounds__(256) void aggregate_kernel(
    const unsigned int* __restrict__ z32, const int* __restrict__ rowptr,
    const float* __restrict__ bnp, float* __restrict__ aggr)
{
    const int n = blockIdx.x * 4 + (threadIdx.x >> 6);
    const int lane = threadIdx.x & 63;
    const int f2 = lane & 31, slot = lane >> 5, f = 2 * f2;
    const float sc0 = bnp[f], sc1 = bnp[f + 1];
    const float sh0 = bnp[128 + f], sh1 = bnp[128 + f + 1];
    const float tc0 = bnp[64 + f], tc1 = bnp[64 + f + 1];
    const float th0 = bnp[192 + f], th1 = bnp[192 + f + 1];
    const int s = rowptr[n], e_end = rowptr[n + 1];
    float a0 = 0.f, a1 = 0.f;
    for (int e = s + slot; e < e_end; e += 2) {
        unsigned int ua = z32[(size_t)e * 64 + f2];
        unsigned int ub = z32[(size_t)e * 64 + 32 + f2];
        float zf0 = fmaf(bflo(ua), sc0, sh0);
        float zf1 = fmaf(bfhi(ua), sc1, sh1);
        float zc0 = fmaf(bflo(ub), tc0, th0);
        float zc1 = fmaf(bfhi(ub), tc1, th1);
        a0 += fmaxf(zf0, 0.f) * fmaxf(zc0, 0.f);
        a1 += fmaxf(zf1, 0.f) * fmaxf(zc1, 0.f);
    }
    a0 += __shfl_xor(a0, 32, 64);
    a1 += __shfl_xor(a1, 32, 64);
    if (slot == 0) {
        float2 w; w.x = a0; w.y = a1;
        *(float2*)&aggr[(size_t)n * 64 + f] = w;
    }
}

// ------------- column stats over [rows,64] -------------
__global__ __launch_bounds__(256) void colstats64_kernel(
    const float* __restrict__ x, int rows, float* __restrict__ stats)
{
    int f = threadIdx.x & 63, sub = threadIdx.x >> 6;
    float s = 0.f, q = 0.f;
    for (int r = blockIdx.x * 4 + sub; r < rows; r += gridDim.x * 4) {
        float v = x[(size_t)r * 64 + f];
        s += v; q = fmaf(v, v, q);
    }
    __shared__ float ls[4][64], lq[4][64];
    ls[sub][f] = s; lq[sub][f] = q;
    __syncthreads();
    if (sub == 0) {
        s = ls[0][f] + ls[1][f] + ls[2][f] + ls[3][f];
        q = lq[0][f] + lq[1][f] + lq[2][f] + lq[3][f];
        atomicAdd(&stats[f], s);
        atomicAdd(&stats[64 + f], q);
    }
}

// ------------- h_next = relu(h + bn2(aggr)) -------------
__global__ __launch_bounds__(256) void update_kernel(
    const float* __restrict__ h, const float* __restrict__ aggr,
    const float* __restrict__ bnp, float* __restrict__ hout)
{
    int t = blockIdx.x * 256 + threadIdx.x;
    int f = t & 63;
    float v = fmaf(aggr[t], bnp[f], bnp[64 + f]);
    hout[t] = fmaxf(h[t] + v, 0.f);
}

// ------------- pooling -------------
__global__ __launch_bounds__(256) void pool_kernel(
    const float* __restrict__ hbuf, const float* __restrict__ ppW,
    const float* __restrict__ ppb, float* __restrict__ out)
{
    const int l = blockIdx.x >> 7, b = blockIdx.x & 127;
    const int wave = threadIdx.x >> 6, lane = threadIdx.x & 63;
    float wcol[64];
#pragma unroll
    for (int k = 0; k < 64; ++k) wcol[k] = ppW[k * 64 + lane];
    const float bias = ppb[lane];
    const float* base = hbuf + ((size_t)l * N_NODES + (size_t)b * 400) * 64;
    __shared__ float srow[4][2][64];
    __shared__ float sacc[4][64];
    float acc = 0.f;
    for (int r = wave * 2; r < 400; r += 8) {
        srow[wave][0][lane] = base[(size_t)r * 64 + lane];
        srow[wave][1][lane] = base[(size_t)r * 64 + 64 + lane];
        float lg0 = bias, lg1 = bias;
#pragma unroll
        for (int k4 = 0; k4 < 64; k4 += 4) {
            float4 a = *(const float4*)&srow[wave][0][k4];
            float4 c = *(const float4*)&srow[wave][1][k4];
            lg0 = fmaf(a.x, wcol[k4 + 0], lg0); lg1 = fmaf(c.x, wcol[k4 + 0], lg1);
            lg0 = fmaf(a.y, wcol[k4 + 1], lg0); lg1 = fmaf(c.y, wcol[k4 + 1], lg1);
            lg0 = fmaf(a.z, wcol[k4 + 2], lg0); lg1 = fmaf(c.z, wcol[k4 + 2], lg1);
            lg0 = fmaf(a.w, wcol[k4 + 3], lg0); lg1 = fmaf(c.w, wcol[k4 + 3], lg1);
        }
        float m0 = lg0, m1 = lg1;
#pragma unroll
        for (int o = 32; o >= 1; o >>= 1) {
            m0 = fmaxf(m0, __shfl_xor(m0, o, 64));
            m1 = fmaxf(m1, __shfl_xor(m1, o, 64));
        }
        float e0 = __expf(lg0 - m0), e1 = __expf(lg1 - m1);
        float s0 = e0, s1 = e1;
#pragma unroll
        for (int o = 32; o >= 1; o >>= 1) {
            s0 += __shfl_xor(s0, o, 64);
            s1 += __shfl_xor(s1, o, 64);
        }
        acc += e0 * (1.0f / s0) + e1 * (1.0f / s1);
    }
    sacc[wave][lane] = acc;
    __syncthreads();
    if (wave == 0) {
        float t = sacc[0][lane] + sacc[1][lane] + sacc[2][lane] + sacc[3][lane];
        atomicAdd(&out[(size_t)b * 64 + lane], t);
    }
}

// ---------------------------------------------------------------------------
extern "C" void kernel_launch(void* const* d_in, const int* in_sizes, int n_in,
                              void* d_out, int out_size, void* d_ws, size_t ws_size,
                              hipStream_t stream)
{
    const float* x        = (const float*)d_in[0];
    const int*   ei       = (const int*)d_in[1];
    const float* ea       = (const float*)d_in[2];
    const float* att      = (const float*)d_in[4];
    const float* embW     = (const float*)d_in[5];
    const float* embB     = (const float*)d_in[6];
    const float* ad_w1    = (const float*)d_in[7];
    const float* ad_b1    = (const float*)d_in[8];
    const float* ad_w2    = (const float*)d_in[9];
    const float* ad_b2    = (const float*)d_in[10];
    const float* ad_alpha = (const float*)d_in[11];
    const float* ad_lut   = (const float*)d_in[12];
    const float* fc_W     = (const float*)d_in[13];
    const float* fc_b     = (const float*)d_in[14];
    const float* bn1_g    = (const float*)d_in[15];
    const float* bn1_b    = (const float*)d_in[16];
    const float* bn2_g    = (const float*)d_in[17];
    const float* bn2_b    = (const float*)d_in[18];
    const float* ppW      = (const float*)d_in[19];
    const float* ppb      = (const float*)d_in[20];
    float* out = (float*)d_out;

    char* ws = (char*)d_ws;
    float* hbuf   = (float*)ws;                                   // 52,428,800 B
    short* zU     = (short*)(ws + 52428800);                      // 157,286,400 B
    float* aggr   = (float*)(ws + 52428800 + 157286400);          // 13,107,200 B
    float* stats1 = (float*)(ws + 222822400);                     // 256
    float* bnp1   = stats1 + 256;                                 // 256
    float* stats2 = bnp1 + 256;                                   // 128
    float* bnp2   = stats2 + 128;                                 // 128  (end: +3072 B)
    int*   rowptr = (int*)(ws + 222825472);                       // 51201 ints (204,804 B)
    int*   cursor = (int*)(ws + 223030784);                       // 51200 ints (cnt alias)
    int*   perm   = (int*)(ws + 223235584);                       // 614400 ints (2,457,600 B)
                                                                  // total ~225.7 MB

    // ---- CSR build (dst is launch-constant) ----
    hipMemsetAsync(cursor, 0, N_NODES * sizeof(int), stream);
    hist_kernel<<<N_EDGES / 256, 256, 0, stream>>>(ei, cursor);
    scan_kernel<<<1, 1024, 0, stream>>>(cursor, rowptr);
    permbuild_kernel<<<N_EDGES / 256, 256, 0, stream>>>(ei, cursor, perm);

    hipMemsetAsync(out, 0, 128 * 64 * sizeof(float), stream);
    embed_kernel<<<512, 256, 0, stream>>>(x, att, embW, embB, hbuf);

    for (int l = 0; l < NCONV; ++l) {
        float* h  = hbuf + (size_t)l * N_NODES * AFL;
        float* hn = h + (size_t)N_NODES * AFL;
        hipMemsetAsync(stats1, 0, 768 * 4, stream);
        edge_kernel<<<256, 512, 0, stream>>>(
            ea, ei, perm, h,
            ad_w1 + l * BINS, ad_b1 + l * BINS,
            ad_w2 + l * BINS * BINS, ad_b2 + l * BINS,
            ad_alpha + l, ad_lut + l * BINS * NFL,
            fc_W + l * 192 * 128, fc_b + l * 128,
            zU, stats1);
        bn_fin_kernel<<<1, 128, 0, stream>>>(stats1, bn1_g + l * 128, bn1_b + l * 128,
                                             bnp1, 128, 1.0f / N_EDGES);
        aggregate_kernel<<<N_NODES / 4, 256, 0, stream>>>((const unsigned int*)zU, rowptr, bnp1, aggr);
        colstats64_kernel<<<256, 256, 0, stream>>>(aggr, N_NODES, stats2);
        bn_fin_kernel<<<1, 128, 0, stream>>>(stats2, bn2_g + l * 64, bn2_b + l * 64,
                                             bnp2, 64, 1.0f / N_NODES);
        update_kernel<<<N_NODES * 64 / 256, 256, 0, stream>>>(h, aggr, bnp2, hn);
    }

    pool_kernel<<<512, 256, 0, stream>>>(hbuf, ppW, ppb, out);
}